// Round 6
// baseline (422.435 us; speedup 1.0000x reference)
//
#include <hip/hip_runtime.h>
#include <hip/hip_bf16.h>
#include <math.h>

typedef __bf16 bf16_t;
typedef __attribute__((ext_vector_type(8))) __bf16 bf16x8;
typedef __attribute__((ext_vector_type(4))) __bf16 bf16x4;
typedef __attribute__((ext_vector_type(4))) float f32x4;

#define LN_EPS 1e-5f
#define RADIUS_F 16.0f

__device__ inline bf16x8 zero8() {
    bf16x8 v;
#pragma unroll
    for (int i = 0; i < 8; ++i) v[i] = (__bf16)0.f;
    return v;
}

__device__ inline float wave_sum(float v) {
#pragma unroll
    for (int o = 1; o < 64; o <<= 1) v += __shfl_xor(v, o);
    return v;
}

__device__ inline void gload_lds16(const bf16_t* g, bf16_t* l) {
    __builtin_amdgcn_global_load_lds(
        (const __attribute__((address_space(1))) void*)g,
        (__attribute__((address_space(3))) void*)l, 16, 0, 0);
}

__device__ inline void drain_barrier() {
    asm volatile("s_waitcnt vmcnt(0)" ::: "memory");
    __builtin_amdgcn_s_barrier();
}

// ---------------- casts (weights only) ----------------
__global__ __launch_bounds__(256) void cast_k(const float* __restrict__ in,
                                              bf16_t* __restrict__ out, int n4) {
    int i = blockIdx.x * 256 + threadIdx.x;
    if (i < n4) {
        float4 v = reinterpret_cast<const float4*>(in)[i];
        bf16x4 o;
        o[0] = (__bf16)v.x; o[1] = (__bf16)v.y; o[2] = (__bf16)v.z; o[3] = (__bf16)v.w;
        reinterpret_cast<bf16x4*>(out)[i] = o;
    }
}

// normalize mem_key rows (896 x 64) -> bf16
__global__ __launch_bounds__(256) void keyn_k(const float* __restrict__ mk,
                                              bf16_t* __restrict__ kn) {
    int row = blockIdx.x * 4 + (threadIdx.x >> 6);
    int lane = threadIdx.x & 63;
    float x = mk[(size_t)row * 64 + lane];
    float ss = wave_sum(x * x);
    kn[(size_t)row * 64 + lane] = (__bf16)(x / fmaxf(sqrtf(ss), 1e-12f));
}

// mem_value: row inv-norms + bf16 copy (padded to 128 rows); zero loss slots
__global__ __launch_bounds__(256) void mv_prep_k(const float* __restrict__ mv,
                                                 bf16_t* __restrict__ mvb,
                                                 float* __restrict__ invmv,
                                                 float* __restrict__ loss_slots) {
    const int s = blockIdx.x, tid = threadIdx.x;
    if (s >= 112) {
        mvb[(size_t)s * 512 + tid * 2] = (__bf16)0.f;
        mvb[(size_t)s * 512 + tid * 2 + 1] = (__bf16)0.f;
        return;
    }
    float2 x = *reinterpret_cast<const float2*>(mv + (size_t)s * 512 + tid * 2);
    float ss = wave_sum(x.x * x.x + x.y * x.y);
    __shared__ float red[4];
    int wid = tid >> 6, lane = tid & 63;
    if (lane == 0) red[wid] = ss;
    __syncthreads();
    ss = red[0] + red[1] + red[2] + red[3];
    if (tid == 0) invmv[s] = 1.f / fmaxf(sqrtf(ss), 1e-12f);
    mvb[(size_t)s * 512 + tid * 2] = (__bf16)x.x;
    mvb[(size_t)s * 512 + tid * 2 + 1] = (__bf16)x.y;
    if (s == 0 && tid < 2) loss_slots[tid] = 0.f;
}

// mem_value transposed + zero-padded to [512][128] bf16
__global__ __launch_bounds__(256) void mvT_k(const float* __restrict__ mv,
                                             bf16_t* __restrict__ mvT) {
    int idx = blockIdx.x * 256 + threadIdx.x;  // 512*128
    int j = idx >> 7, s = idx & 127;
    mvT[idx] = (__bf16)(s < 112 ? mv[(size_t)s * 512 + j] : 0.f);
}

// contrastive loss: sum |I - Gn Gn^T| * 0.01  (fp32)
__global__ __launch_bounds__(256) void contrastive_k(const float* __restrict__ mv,
                                                     const float* __restrict__ invmv,
                                                     float* __restrict__ out_slot) {
    const int a = blockIdx.x;
    const int tid = threadIdx.x, wid = tid >> 6, lane = tid & 63;
    __shared__ float rowa[512];
    __shared__ float wsum[4];
    for (int i = tid; i < 512; i += 256) rowa[i] = mv[(size_t)a * 512 + i];
    __syncthreads();
    float acc = 0.f;
    const float ia = invmv[a];
    for (int b = wid; b < 112; b += 4) {
        float d = 0.f;
#pragma unroll
        for (int i = 0; i < 8; ++i) d += rowa[lane + i * 64] * mv[(size_t)b * 512 + lane + i * 64];
        d = wave_sum(d);
        float gv = d * ia * invmv[b];
        acc += fabsf((a == b ? 1.f : 0.f) - gv);
    }
    if (lane == 0) wsum[wid] = acc;
    __syncthreads();
    if (tid == 0) atomicAdd(out_slot, (wsum[0] + wsum[1] + wsum[2] + wsum[3]) * 0.01f);
}

// ---------------- 128x128 LDS-staged GEMM, A = fp32 (reg-staged + cvt) ----------------
__global__ __launch_bounds__(256) void gemm128_f32a(
    const float* __restrict__ A, int lda,
    const bf16_t* __restrict__ W, int ldw,
    const float* __restrict__ bias,
    bf16_t* __restrict__ Cb, int ldc, int K) {
    __shared__ __align__(16) bf16_t As[128 * 32];
    __shared__ __align__(16) bf16_t Bs[128 * 32];
    const int tid = threadIdx.x;
    const int wid = tid >> 6, lane = tid & 63;
    const int wr = wid >> 1, wc = wid & 1;
    const int lr = lane & 15;
    const int ko = (lane >> 4) * 8;
    const size_t rowBase = (size_t)blockIdx.x * 128;
    const size_t colBase = (size_t)blockIdx.y * 128;
    const int r0 = tid >> 2;
    const int c0 = (tid & 3) * 8;
    const float* a_src = A + (rowBase + r0) * lda + c0;
    const bf16_t* w_src = W + (colBase + r0) * ldw + c0;
    f32x4 acc[4][4];
#pragma unroll
    for (int m = 0; m < 4; ++m)
#pragma unroll
        for (int n = 0; n < 4; ++n) {
            acc[m][n][0] = 0.f; acc[m][n][1] = 0.f;
            acc[m][n][2] = 0.f; acc[m][n][3] = 0.f;
        }
    for (int k0 = 0; k0 < K; k0 += 32) {
        float4 a0 = *reinterpret_cast<const float4*>(a_src + k0);
        float4 a1 = *reinterpret_cast<const float4*>(a_src + k0 + 4);
        float4 a2 = *reinterpret_cast<const float4*>(a_src + (size_t)64 * lda + k0);
        float4 a3 = *reinterpret_cast<const float4*>(a_src + (size_t)64 * lda + k0 + 4);
        __syncthreads();
        gload_lds16(w_src + k0, Bs + tid * 8);
        gload_lds16(w_src + (size_t)64 * ldw + k0, Bs + 2048 + tid * 8);
        bf16x8 p0, p1;
        p0[0] = (__bf16)a0.x; p0[1] = (__bf16)a0.y; p0[2] = (__bf16)a0.z; p0[3] = (__bf16)a0.w;
        p0[4] = (__bf16)a1.x; p0[5] = (__bf16)a1.y; p0[6] = (__bf16)a1.z; p0[7] = (__bf16)a1.w;
        p1[0] = (__bf16)a2.x; p1[1] = (__bf16)a2.y; p1[2] = (__bf16)a2.z; p1[3] = (__bf16)a2.w;
        p1[4] = (__bf16)a3.x; p1[5] = (__bf16)a3.y; p1[6] = (__bf16)a3.z; p1[7] = (__bf16)a3.w;
        *reinterpret_cast<bf16x8*>(As + tid * 8) = p0;
        *reinterpret_cast<bf16x8*>(As + 2048 + tid * 8) = p1;
        __syncthreads();
        bf16x8 af[4], bfr[4];
#pragma unroll
        for (int m = 0; m < 4; ++m)
            af[m] = *reinterpret_cast<const bf16x8*>(As + (wr * 64 + m * 16 + lr) * 32 + ko);
#pragma unroll
        for (int n = 0; n < 4; ++n)
            bfr[n] = *reinterpret_cast<const bf16x8*>(Bs + (wc * 64 + n * 16 + lr) * 32 + ko);
#pragma unroll
        for (int m = 0; m < 4; ++m)
#pragma unroll
            for (int n = 0; n < 4; ++n)
                acc[m][n] = __builtin_amdgcn_mfma_f32_16x16x32_bf16(af[m], bfr[n], acc[m][n], 0, 0, 0);
    }
    const int rj = (lane >> 4) * 4;
#pragma unroll
    for (int n = 0; n < 4; ++n) {
        const int col = (int)colBase + wc * 64 + n * 16 + lr;
        const float bv = bias ? bias[col] : 0.f;
#pragma unroll
        for (int m = 0; m < 4; ++m) {
            const size_t r = rowBase + wr * 64 + m * 16 + rj;
#pragma unroll
            for (int j = 0; j < 4; ++j)
                Cb[(r + j) * ldc + col] = (__bf16)(acc[m][n][j] + bv);
        }
    }
}

// ---------------- 128x128 LDS-staged GEMM, bf16 A, f32 out (+bias) ----------------
// C[M,N](f32) = A[M,K] * W[N,K]^T + bias; grid = (M/128, N/128)
__global__ __launch_bounds__(256) void gemm128_bias(
    const bf16_t* __restrict__ A, int lda,
    const bf16_t* __restrict__ W, int ldw,
    const float* __restrict__ bias,
    float* __restrict__ Cf, int ldc, int K) {
    __shared__ __align__(16) bf16_t As[128 * 32];
    __shared__ __align__(16) bf16_t Bs[128 * 32];
    const int tid = threadIdx.x;
    const int wid = tid >> 6, lane = tid & 63;
    const int wr = wid >> 1, wc = wid & 1;
    const int lr = lane & 15;
    const int ko = (lane >> 4) * 8;
    const size_t rowBase = (size_t)blockIdx.x * 128;
    const size_t colBase = (size_t)blockIdx.y * 128;
    const int r0 = tid >> 2;
    const int c0 = (tid & 3) * 8;
    const bf16_t* a_src = A + (rowBase + r0) * lda + c0;
    const bf16_t* w_src = W + (colBase + r0) * ldw + c0;
    f32x4 acc[4][4];
#pragma unroll
    for (int m = 0; m < 4; ++m)
#pragma unroll
        for (int n = 0; n < 4; ++n) {
            acc[m][n][0] = 0.f; acc[m][n][1] = 0.f;
            acc[m][n][2] = 0.f; acc[m][n][3] = 0.f;
        }
    for (int k0 = 0; k0 < K; k0 += 32) {
        __syncthreads();
        gload_lds16(a_src + k0, As + tid * 8);
        gload_lds16(a_src + (size_t)64 * lda + k0, As + 2048 + tid * 8);
        gload_lds16(w_src + k0, Bs + tid * 8);
        gload_lds16(w_src + (size_t)64 * ldw + k0, Bs + 2048 + tid * 8);
        __syncthreads();
        bf16x8 af[4], bfr[4];
#pragma unroll
        for (int m = 0; m < 4; ++m)
            af[m] = *reinterpret_cast<const bf16x8*>(As + (wr * 64 + m * 16 + lr) * 32 + ko);
#pragma unroll
        for (int n = 0; n < 4; ++n)
            bfr[n] = *reinterpret_cast<const bf16x8*>(Bs + (wc * 64 + n * 16 + lr) * 32 + ko);
#pragma unroll
        for (int m = 0; m < 4; ++m)
#pragma unroll
            for (int n = 0; n < 4; ++n)
                acc[m][n] = __builtin_amdgcn_mfma_f32_16x16x32_bf16(af[m], bfr[n], acc[m][n], 0, 0, 0);
    }
    const int rj = (lane >> 4) * 4;
#pragma unroll
    for (int n = 0; n < 4; ++n) {
        const int col = (int)colBase + wc * 64 + n * 16 + lr;
        const float bv = bias ? bias[col] : 0.f;
#pragma unroll
        for (int m = 0; m < 4; ++m) {
            const size_t r = rowBase + wr * 64 + m * 16 + rj;
#pragma unroll
            for (int j = 0; j < 4; ++j)
                Cf[(r + j) * ldc + col] = acc[m][n][j] + bv;
        }
    }
}

// ---------------- small direct GEMM (WcT fold only) ----------------
__global__ __launch_bounds__(256) void gemm_bt(
    const bf16_t* __restrict__ A, int lda, int aZ,
    const bf16_t* __restrict__ W, int ldw, int wZ,
    bf16_t* __restrict__ Cb, int ldc, int cZ,
    int M, int N, int K) {
    const int wid = threadIdx.x >> 6;
    const int lane = threadIdx.x & 63;
    const int lr = lane & 15;
    const int kk = (lane >> 4) * 8;
    const int row0 = blockIdx.x * 64 + wid * 16;
    const int col0 = blockIdx.y * 64;
    A += (size_t)blockIdx.z * aZ;
    W += (size_t)blockIdx.z * wZ;
    const bf16_t* a_ptr = A + (size_t)(row0 + lr) * lda + kk;
    const bf16_t* w_ptr = W + (size_t)(col0 + lr) * ldw + kk;
    f32x4 acc[4];
#pragma unroll
    for (int t = 0; t < 4; ++t) { acc[t][0] = 0.f; acc[t][1] = 0.f; acc[t][2] = 0.f; acc[t][3] = 0.f; }
    bool colv[4];
#pragma unroll
    for (int t = 0; t < 4; ++t) colv[t] = (col0 + t * 16 + lr) < N;
    for (int k0 = 0; k0 < K; k0 += 32) {
        bf16x8 a = *reinterpret_cast<const bf16x8*>(a_ptr + k0);
#pragma unroll
        for (int t = 0; t < 4; ++t) {
            bf16x8 b;
            if (colv[t]) b = *reinterpret_cast<const bf16x8*>(w_ptr + (size_t)t * 16 * ldw + k0);
            else b = zero8();
            acc[t] = __builtin_amdgcn_mfma_f32_16x16x32_bf16(a, b, acc[t], 0, 0, 0);
        }
    }
    const int rb = (lane >> 4) * 4;
    Cb += (size_t)blockIdx.z * cZ;
#pragma unroll
    for (int t = 0; t < 4; ++t) {
        int col = col0 + t * 16 + lr;
        if (col >= N) continue;
#pragma unroll
        for (int j = 0; j < 4; ++j) {
            int r = row0 + rb + j;
            Cb[(size_t)r * ldc + col] = (__bf16)acc[t][j];
        }
    }
}

// ---------------- predict addressing: sim -> softmax -> addr bf16 [N,896] ----------------
__global__ __launch_bounds__(256) void addr_predict(const bf16_t* __restrict__ qp,
                                                    const bf16_t* __restrict__ keyn,
                                                    bf16_t* __restrict__ addr) {
    const int wid = threadIdx.x >> 6, lane = threadIdx.x & 63;
    const int lr = lane & 15, kk = (lane >> 4) * 8;
    const int h = blockIdx.y;
    const int row0 = blockIdx.x * 64 + wid * 16;
    const bf16_t* a_ptr = qp + (size_t)(row0 + lr) * 512 + h * 64 + kk;
    bf16x8 a0 = *reinterpret_cast<const bf16x8*>(a_ptr);
    bf16x8 a1 = *reinterpret_cast<const bf16x8*>(a_ptr + 32);
    float ssq = 0.f;
#pragma unroll
    for (int j = 0; j < 8; ++j) {
        float x = (float)a0[j], y = (float)a1[j];
        ssq += x * x + y * y;
    }
    ssq += __shfl_xor(ssq, 16);
    ssq += __shfl_xor(ssq, 32);
    const float invq = 1.f / fmaxf(sqrtf(ssq), 1e-12f);
    f32x4 acc[7];
#pragma unroll
    for (int t = 0; t < 7; ++t) {
        const bf16_t* b_ptr = keyn + (size_t)(h * 112 + t * 16 + lr) * 64 + kk;
        bf16x8 b0 = *reinterpret_cast<const bf16x8*>(b_ptr);
        bf16x8 b1 = *reinterpret_cast<const bf16x8*>(b_ptr + 32);
        f32x4 c; c[0] = 0.f; c[1] = 0.f; c[2] = 0.f; c[3] = 0.f;
        c = __builtin_amdgcn_mfma_f32_16x16x32_bf16(a0, b0, c, 0, 0, 0);
        c = __builtin_amdgcn_mfma_f32_16x16x32_bf16(a1, b1, c, 0, 0, 0);
        acc[t] = c;
    }
    const int rb = (lane >> 4) * 4;
    float iq[4];
#pragma unroll
    for (int j = 0; j < 4; ++j) iq[j] = __shfl(invq, rb + j);
#pragma unroll
    for (int j = 0; j < 4; ++j) {
        float m = -1e30f;
#pragma unroll
        for (int t = 0; t < 7; ++t) { acc[t][j] *= iq[j] * RADIUS_F; m = fmaxf(m, acc[t][j]); }
#pragma unroll
        for (int o = 1; o < 16; o <<= 1) m = fmaxf(m, __shfl_xor(m, o));
        float s = 0.f;
#pragma unroll
        for (int t = 0; t < 7; ++t) { float e = __expf(acc[t][j] - m); acc[t][j] = e; s += e; }
#pragma unroll
        for (int o = 1; o < 16; o <<= 1) s += __shfl_xor(s, o);
        const float rs = 1.f / s;
#pragma unroll
        for (int t = 0; t < 7; ++t) acc[t][j] *= rs;
    }
#pragma unroll
    for (int t = 0; t < 7; ++t)
#pragma unroll
        for (int j = 0; j < 4; ++j)
            addr[(size_t)(row0 + rb + j) * 896 + h * 112 + t * 16 + lr] = (__bf16)acc[t][j];
}

// ---------------- fused recon sim GEMM + softmax -> addr2 [M][128] ----------------
__global__ __launch_bounds__(256, 2) void gemm_sim_softmax(
    const bf16_t* __restrict__ vp,   // [M][512]
    const bf16_t* __restrict__ mvb,  // [128][512] (rows 112..127 zero)
    const float* __restrict__ invmv, // [112]
    bf16_t* __restrict__ addr2) {    // [M][128]
    __shared__ __align__(16) bf16_t As[2][128 * 32];
    __shared__ __align__(16) bf16_t Bs[2][128 * 32];
    const int tid = threadIdx.x;
    const int wid = tid >> 6, lane = tid & 63;
    const int lr = lane & 15, hi = lane >> 4;
    const int ko = hi * 8;
    const size_t rowBase = (size_t)blockIdx.x * 128;
    const int r0 = tid >> 2, c0 = (tid & 3) * 8;
    const bf16_t* a_src = vp + (rowBase + r0) * 512 + c0;
    const bf16_t* b_src = mvb + (size_t)r0 * 512 + c0;
    f32x4 acc[2][8];
#pragma unroll
    for (int m = 0; m < 2; ++m)
#pragma unroll
        for (int n = 0; n < 8; ++n) {
            acc[m][n][0] = 0.f; acc[m][n][1] = 0.f;
            acc[m][n][2] = 0.f; acc[m][n][3] = 0.f;
        }
    float ssq[2] = {0.f, 0.f};
    auto stage = [&](int buf, int ks) {
        const int k0 = ks * 32;
        gload_lds16(a_src + k0, &As[buf][tid * 8]);
        gload_lds16(a_src + (size_t)64 * 512 + k0, &As[buf][2048 + tid * 8]);
        gload_lds16(b_src + k0, &Bs[buf][tid * 8]);
        gload_lds16(b_src + (size_t)64 * 512 + k0, &Bs[buf][2048 + tid * 8]);
    };
    stage(0, 0);
    drain_barrier();
    int cur = 0;
    for (int ks = 0; ks < 16; ++ks) {
        if (ks < 15) stage(cur ^ 1, ks + 1);
        bf16x8 af[2], bfr[8];
#pragma unroll
        for (int m = 0; m < 2; ++m)
            af[m] = *reinterpret_cast<const bf16x8*>(&As[cur][(wid * 32 + m * 16 + lr) * 32 + ko]);
#pragma unroll
        for (int n = 0; n < 8; ++n)
            bfr[n] = *reinterpret_cast<const bf16x8*>(&Bs[cur][(n * 16 + lr) * 32 + ko]);
#pragma unroll
        for (int m = 0; m < 2; ++m) {
#pragma unroll
            for (int j = 0; j < 8; ++j) { float x = (float)af[m][j]; ssq[m] += x * x; }
#pragma unroll
            for (int n = 0; n < 8; ++n)
                acc[m][n] = __builtin_amdgcn_mfma_f32_16x16x32_bf16(af[m], bfr[n], acc[m][n], 0, 0, 0);
        }
        drain_barrier();
        cur ^= 1;
    }
#pragma unroll
    for (int m = 0; m < 2; ++m) {
        ssq[m] += __shfl_xor(ssq[m], 16);
        ssq[m] += __shfl_xor(ssq[m], 32);
        ssq[m] = 1.f / fmaxf(sqrtf(ssq[m]), 1e-12f);
    }
    const int rb = hi * 4;
    float imv[7];
#pragma unroll
    for (int n = 0; n < 7; ++n) imv[n] = invmv[n * 16 + lr];
#pragma unroll
    for (int m = 0; m < 2; ++m)
#pragma unroll
        for (int j = 0; j < 4; ++j) {
            const float iq = __shfl(ssq[m], (lane & 48) | (rb + j));
            float x[7];
            float mx = -1e30f;
#pragma unroll
            for (int n = 0; n < 7; ++n) {
                x[n] = acc[m][n][j] * iq * imv[n] * RADIUS_F;
                mx = fmaxf(mx, x[n]);
            }
#pragma unroll
            for (int o = 1; o < 16; o <<= 1) mx = fmaxf(mx, __shfl_xor(mx, o));
            float s = 0.f;
#pragma unroll
            for (int n = 0; n < 7; ++n) { x[n] = __expf(x[n] - mx); s += x[n]; }
#pragma unroll
            for (int o = 1; o < 16; o <<= 1) s += __shfl_xor(s, o);
            const float rs = 1.f / s;
            const size_t row = rowBase + wid * 32 + m * 16 + rb + j;
#pragma unroll
            for (int n = 0; n < 7; ++n)
                addr2[row * 128 + n * 16 + lr] = (__bf16)(x[n] * rs);
            addr2[row * 128 + 112 + lr] = (__bf16)0.f;
        }
}

// ---------------- streaming LN (predict): io = LN1(query + io), in place ----------------
// one wave per row; float4 x2 per lane (fully coalesced, 1KB/wave/instr)
__global__ __launch_bounds__(256) void ln_stream(
    float* __restrict__ io, const float* __restrict__ query,
    const float* __restrict__ g, const float* __restrict__ b) {
    const int wid = threadIdx.x >> 6, lane = threadIdx.x & 63;
    const size_t row = (size_t)blockIdx.x * 4 + wid;
    const size_t base = row * 512;
    const int c1 = lane * 4, c2 = 256 + lane * 4;
    float4 a1 = *reinterpret_cast<const float4*>(io + base + c1);
    float4 a2 = *reinterpret_cast<const float4*>(io + base + c2);
    float4 q1 = *reinterpret_cast<const float4*>(query + base + c1);
    float4 q2 = *reinterpret_cast<const float4*>(query + base + c2);
    float4 x1 = make_float4(a1.x + q1.x, a1.y + q1.y, a1.z + q1.z, a1.w + q1.w);
    float4 x2 = make_float4(a2.x + q2.x, a2.y + q2.y, a2.z + q2.z, a2.w + q2.w);
    float s1 = x1.x + x1.y + x1.z + x1.w + x2.x + x2.y + x2.z + x2.w;
    float s2 = x1.x * x1.x + x1.y * x1.y + x1.z * x1.z + x1.w * x1.w +
               x2.x * x2.x + x2.y * x2.y + x2.z * x2.z + x2.w * x2.w;
    s1 = wave_sum(s1);
    s2 = wave_sum(s2);
    const float mu = s1 * (1.f / 512.f);
    const float r = rsqrtf(s2 * (1.f / 512.f) - mu * mu + LN_EPS);
    float4 g1v = *reinterpret_cast<const float4*>(g + c1);
    float4 g2v = *reinterpret_cast<const float4*>(g + c2);
    float4 b1v = *reinterpret_cast<const float4*>(b + c1);
    float4 b2v = *reinterpret_cast<const float4*>(b + c2);
    float4 o1 = make_float4((x1.x - mu) * r * g1v.x + b1v.x, (x1.y - mu) * r * g1v.y + b1v.y,
                            (x1.z - mu) * r * g1v.z + b1v.z, (x1.w - mu) * r * g1v.w + b1v.w);
    float4 o2 = make_float4((x2.x - mu) * r * g2v.x + b2v.x, (x2.y - mu) * r * g2v.y + b2v.y,
                            (x2.z - mu) * r * g2v.z + b2v.z, (x2.w - mu) * r * g2v.w + b2v.w);
    *reinterpret_cast<float4*>(io + base + c1) = o1;
    *reinterpret_cast<float4*>(io + base + c2) = o2;
}

// ---------------- streaming recon epilogue: cos-loss + LN3 + LN1, in place ----------------
__global__ __launch_bounds__(256) void recon_ep_stream(
    float* __restrict__ io,          // attn_recon in, f_target_recon out
    const float* __restrict__ query, const float* __restrict__ value,
    const float* __restrict__ g3, const float* __restrict__ b3,
    const float* __restrict__ g1, const float* __restrict__ b1,
    float* __restrict__ loss0) {
    const int wid = threadIdx.x >> 6, lane = threadIdx.x & 63;
    const size_t row = (size_t)blockIdx.x * 4 + wid;
    const size_t base = row * 512;
    const int c1 = lane * 4, c2 = 256 + lane * 4;
    float4 a1 = *reinterpret_cast<const float4*>(io + base + c1);
    float4 a2 = *reinterpret_cast<const float4*>(io + base + c2);
    float4 v1 = *reinterpret_cast<const float4*>(value + base + c1);
    float4 v2 = *reinterpret_cast<const float4*>(value + base + c2);
    float sa = a1.x + a1.y + a1.z + a1.w + a2.x + a2.y + a2.z + a2.w;
    float sa2 = a1.x * a1.x + a1.y * a1.y + a1.z * a1.z + a1.w * a1.w +
                a2.x * a2.x + a2.y * a2.y + a2.z * a2.z + a2.w * a2.w;
    float sav = a1.x * v1.x + a1.y * v1.y + a1.z * v1.z + a1.w * v1.w +
                a2.x * v2.x + a2.y * v2.y + a2.z * v2.z + a2.w * v2.w;
    float sv2 = v1.x * v1.x + v1.y * v1.y + v1.z * v1.z + v1.w * v1.w +
                v2.x * v2.x + v2.y * v2.y + v2.z * v2.z + v2.w * v2.w;
    sa = wave_sum(sa);
    sa2 = wave_sum(sa2);
    sav = wave_sum(sav);
    sv2 = wave_sum(sv2);
    __shared__ float rred[4];
    if (lane == 0) {
        const float na = fmaxf(sqrtf(sa2), 1e-12f);
        const float nv = fmaxf(sqrtf(sv2), 1e-12f);
        rred[wid] = fabsf(1.f - sav / (na * nv));
    }
    const float mu3 = sa * (1.f / 512.f);
    const float r3 = rsqrtf(sa2 * (1.f / 512.f) - mu3 * mu3 + LN_EPS);
    float4 q1 = *reinterpret_cast<const float4*>(query + base + c1);
    float4 q2 = *reinterpret_cast<const float4*>(query + base + c2);
    float4 g3a = *reinterpret_cast<const float4*>(g3 + c1);
    float4 g3b = *reinterpret_cast<const float4*>(g3 + c2);
    float4 b3a = *reinterpret_cast<const float4*>(b3 + c1);
    float4 b3b = *reinterpret_cast<const float4*>(b3 + c2);
    float4 x1 = make_float4(q1.x + (a1.x - mu3) * r3 * g3a.x + b3a.x,
                            q1.y + (a1.y - mu3) * r3 * g3a.y + b3a.y,
                            q1.z + (a1.z - mu3) * r3 * g3a.z + b3a.z,
                            q1.w + (a1.w - mu3) * r3 * g3a.w + b3a.w);
    float4 x2 = make_float4(q2.x + (a2.x - mu3) * r3 * g3b.x + b3b.x,
                            q2.y + (a2.y - mu3) * r3 * g3b.y + b3b.y,
                            q2.z + (a2.z - mu3) * r3 * g3b.z + b3b.z,
                            q2.w + (a2.w - mu3) * r3 * g3b.w + b3b.w);
    float s1 = x1.x + x1.y + x1.z + x1.w + x2.x + x2.y + x2.z + x2.w;
    float s2 = x1.x * x1.x + x1.y * x1.y + x1.z * x1.z + x1.w * x1.w +
               x2.x * x2.x + x2.y * x2.y + x2.z * x2.z + x2.w * x2.w;
    s1 = wave_sum(s1);
    s2 = wave_sum(s2);
    const float mu = s1 * (1.f / 512.f);
    const float r = rsqrtf(s2 * (1.f / 512.f) - mu * mu + LN_EPS);
    float4 g1a = *reinterpret_cast<const float4*>(g1 + c1);
    float4 g1b = *reinterpret_cast<const float4*>(g1 + c2);
    float4 b1a = *reinterpret_cast<const float4*>(b1 + c1);
    float4 b1b = *reinterpret_cast<const float4*>(b1 + c2);
    float4 o1 = make_float4((x1.x - mu) * r * g1a.x + b1a.x, (x1.y - mu) * r * g1a.y + b1a.y,
                            (x1.z - mu) * r * g1a.z + b1a.z, (x1.w - mu) * r * g1a.w + b1a.w);
    float4 o2 = make_float4((x2.x - mu) * r * g1b.x + b1b.x, (x2.y - mu) * r * g1b.y + b1b.y,
                            (x2.z - mu) * r * g1b.z + b1b.z, (x2.w - mu) * r * g1b.w + b1b.w);
    *reinterpret_cast<float4*>(io + base + c1) = o1;
    *reinterpret_cast<float4*>(io + base + c2) = o2;
    __syncthreads();
    if (threadIdx.x == 0)
        atomicAdd(loss0, (rred[0] + rred[1] + rred[2] + rred[3]) * (1.f / 32768.f));
}

extern "C" void kernel_launch(void* const* d_in, const int* in_sizes, int n_in,
                              void* d_out, int out_size, void* d_ws, size_t ws_size,
                              hipStream_t stream) {
    const float* query = (const float*)d_in[0];
    const float* value = (const float*)d_in[1];
    const float* mem_key = (const float*)d_in[2];
    const float* mem_value = (const float*)d_in[3];
    const float* q_w = (const float*)d_in[4];
    const float* q_b = (const float*)d_in[5];
    const float* v_w = (const float*)d_in[6];
    const float* v_b = (const float*)d_in[7];
    const float* out_w = (const float*)d_in[8];
    const float* out_b = (const float*)d_in[9];
    const float* ln1_g = (const float*)d_in[10];
    const float* ln1_b = (const float*)d_in[11];
    const float* ln3_g = (const float*)d_in[12];
    const float* ln3_b = (const float*)d_in[13];
    float* out = (float*)d_out;

    char* ws = (char*)d_ws;
    size_t off = 0;
    auto alloc = [&](size_t bytes) {
        void* p = ws + off;
        off += (bytes + 255) & ~(size_t)255;
        return p;
    };
    bf16_t* bufB = (bf16_t*)alloc(16777216ull * 2);    // qp_bf16, then v_proj_bf16
    bf16_t* addr = (bf16_t*)alloc(32768ull * 896 * 2); // addr, later addr2
    bf16_t* qwb = (bf16_t*)alloc(262144ull * 2);
    bf16_t* vwb = (bf16_t*)alloc(262144ull * 2);
    bf16_t* owb = (bf16_t*)alloc(2097152ull * 2);
    bf16_t* wct = (bf16_t*)alloc(896ull * 512 * 2);    // WcT[512][896]
    bf16_t* keyn = (bf16_t*)alloc(896ull * 64 * 2);
    bf16_t* mvb = (bf16_t*)alloc(128ull * 512 * 2);    // padded to 128 rows
    bf16_t* mvT = (bf16_t*)alloc(512ull * 128 * 2);
    float* invmv = (float*)alloc(112 * 4);
    bf16_t* addr2 = addr;

    float* f_predict = out;               // also attn_out staging (f32)
    float* f_recon = out + 16777216;      // also attn_recon staging (f32)
    float* loss_slots = out + 33554432;   // [recon_loss, contrastive_loss]

    // prep
    cast_k<<<256, 256, 0, stream>>>(q_w, qwb, 65536);
    cast_k<<<256, 256, 0, stream>>>(v_w, vwb, 65536);
    cast_k<<<2048, 256, 0, stream>>>(out_w, owb, 524288);
    keyn_k<<<224, 256, 0, stream>>>(mem_key, keyn);
    mv_prep_k<<<128, 256, 0, stream>>>(mem_value, mvb, invmv, loss_slots);
    mvT_k<<<256, 256, 0, stream>>>(mem_value, mvT);
    contrastive_k<<<112, 256, 0, stream>>>(mem_value, invmv, loss_slots + 1);
    // WcT[d][h*112+s] = sum_j out_w[d][h*512+j] * mem_value[s][j]
    gemm_bt<<<dim3(8, 2, 8), 256, 0, stream>>>(owb, 4096, 512, mvb, 512, 0,
                                               wct, 896, 112, 512, 112, 512);
    // predict branch
    gemm128_f32a<<<dim3(256, 4), 256, 0, stream>>>(query, 512, qwb, 512, q_b,
                                                   bufB, 512, 512);
    addr_predict<<<dim3(512, 8), 256, 0, stream>>>(bufB, keyn, addr);
    gemm128_bias<<<dim3(256, 4), 256, 0, stream>>>(addr, 896, wct, 896, out_b,
                                                   f_predict, 512, 896);
    ln_stream<<<8192, 256, 0, stream>>>(f_predict, query, ln1_g, ln1_b);
    // recon branch
    gemm128_f32a<<<dim3(256, 4), 256, 0, stream>>>(value, 512, vwb, 512, v_b,
                                                   bufB, 512, 512);
    gemm_sim_softmax<<<256, 256, 0, stream>>>(bufB, mvb, invmv, addr2);
    gemm128_bias<<<dim3(256, 4), 256, 0, stream>>>(addr2, 128, mvT, 128,
                                                   (const float*)nullptr,
                                                   f_recon, 512, 128);
    recon_ep_stream<<<8192, 256, 0, stream>>>(f_recon, query, value,
                                              ln3_g, ln3_b, ln1_g, ln1_b,
                                              loss_slots);
}

// Round 7
// 357.525 us; speedup vs baseline: 1.1816x; 1.1816x over previous
//
#include <hip/hip_runtime.h>
#include <hip/hip_bf16.h>
#include <math.h>

typedef __bf16 bf16_t;
typedef __attribute__((ext_vector_type(8))) __bf16 bf16x8;
typedef __attribute__((ext_vector_type(4))) __bf16 bf16x4;
typedef __attribute__((ext_vector_type(4))) float f32x4;

#define LN_EPS 1e-5f
#define RADIUS_F 16.0f

__device__ inline bf16x8 zero8() {
    bf16x8 v;
#pragma unroll
    for (int i = 0; i < 8; ++i) v[i] = (__bf16)0.f;
    return v;
}

__device__ inline float wave_sum(float v) {
#pragma unroll
    for (int o = 1; o < 64; o <<= 1) v += __shfl_xor(v, o);
    return v;
}

__device__ inline void gload_lds16(const bf16_t* g, bf16_t* l) {
    __builtin_amdgcn_global_load_lds(
        (const __attribute__((address_space(1))) void*)g,
        (__attribute__((address_space(3))) void*)l, 16, 0, 0);
}

__device__ inline void drain_barrier() {
    asm volatile("s_waitcnt vmcnt(0)" ::: "memory");
    __builtin_amdgcn_s_barrier();
}

// ---------------- casts (weights only) ----------------
__global__ __launch_bounds__(256) void cast_k(const float* __restrict__ in,
                                              bf16_t* __restrict__ out, int n4) {
    int i = blockIdx.x * 256 + threadIdx.x;
    if (i < n4) {
        float4 v = reinterpret_cast<const float4*>(in)[i];
        bf16x4 o;
        o[0] = (__bf16)v.x; o[1] = (__bf16)v.y; o[2] = (__bf16)v.z; o[3] = (__bf16)v.w;
        reinterpret_cast<bf16x4*>(out)[i] = o;
    }
}

// normalize mem_key rows (896 x 64) -> bf16
__global__ __launch_bounds__(256) void keyn_k(const float* __restrict__ mk,
                                              bf16_t* __restrict__ kn) {
    int row = blockIdx.x * 4 + (threadIdx.x >> 6);
    int lane = threadIdx.x & 63;
    float x = mk[(size_t)row * 64 + lane];
    float ss = wave_sum(x * x);
    kn[(size_t)row * 64 + lane] = (__bf16)(x / fmaxf(sqrtf(ss), 1e-12f));
}

// mem_value: row inv-norms + bf16 copy (padded to 128 rows); zero loss slots
__global__ __launch_bounds__(256) void mv_prep_k(const float* __restrict__ mv,
                                                 bf16_t* __restrict__ mvb,
                                                 float* __restrict__ invmv,
                                                 float* __restrict__ loss_slots) {
    const int s = blockIdx.x, tid = threadIdx.x;
    if (s >= 112) {
        mvb[(size_t)s * 512 + tid * 2] = (__bf16)0.f;
        mvb[(size_t)s * 512 + tid * 2 + 1] = (__bf16)0.f;
        return;
    }
    float2 x = *reinterpret_cast<const float2*>(mv + (size_t)s * 512 + tid * 2);
    float ss = wave_sum(x.x * x.x + x.y * x.y);
    __shared__ float red[4];
    int wid = tid >> 6, lane = tid & 63;
    if (lane == 0) red[wid] = ss;
    __syncthreads();
    ss = red[0] + red[1] + red[2] + red[3];
    if (tid == 0) invmv[s] = 1.f / fmaxf(sqrtf(ss), 1e-12f);
    mvb[(size_t)s * 512 + tid * 2] = (__bf16)x.x;
    mvb[(size_t)s * 512 + tid * 2 + 1] = (__bf16)x.y;
    if (s == 0 && tid < 2) loss_slots[tid] = 0.f;
}

// mem_value transposed + zero-padded to [512][128] bf16
__global__ __launch_bounds__(256) void mvT_k(const float* __restrict__ mv,
                                             bf16_t* __restrict__ mvT) {
    int idx = blockIdx.x * 256 + threadIdx.x;  // 512*128
    int j = idx >> 7, s = idx & 127;
    mvT[idx] = (__bf16)(s < 112 ? mv[(size_t)s * 512 + j] : 0.f);
}

// contrastive loss: sum |I - Gn Gn^T| * 0.01  (fp32)
__global__ __launch_bounds__(256) void contrastive_k(const float* __restrict__ mv,
                                                     const float* __restrict__ invmv,
                                                     float* __restrict__ out_slot) {
    const int a = blockIdx.x;
    const int tid = threadIdx.x, wid = tid >> 6, lane = tid & 63;
    __shared__ float rowa[512];
    __shared__ float wsum[4];
    for (int i = tid; i < 512; i += 256) rowa[i] = mv[(size_t)a * 512 + i];
    __syncthreads();
    float acc = 0.f;
    const float ia = invmv[a];
    for (int b = wid; b < 112; b += 4) {
        float d = 0.f;
#pragma unroll
        for (int i = 0; i < 8; ++i) d += rowa[lane + i * 64] * mv[(size_t)b * 512 + lane + i * 64];
        d = wave_sum(d);
        float gv = d * ia * invmv[b];
        acc += fabsf((a == b ? 1.f : 0.f) - gv);
    }
    if (lane == 0) wsum[wid] = acc;
    __syncthreads();
    if (tid == 0) atomicAdd(out_slot, (wsum[0] + wsum[1] + wsum[2] + wsum[3]) * 0.01f);
}

// ---------------- 128x128 LDS-staged GEMM, A = fp32 (reg-staged + cvt) ----------------
__global__ __launch_bounds__(256) void gemm128_f32a(
    const float* __restrict__ A, int lda,
    const bf16_t* __restrict__ W, int ldw,
    const float* __restrict__ bias,
    bf16_t* __restrict__ Cb, int ldc, int K) {
    __shared__ __align__(16) bf16_t As[128 * 32];
    __shared__ __align__(16) bf16_t Bs[128 * 32];
    const int tid = threadIdx.x;
    const int wid = tid >> 6, lane = tid & 63;
    const int wr = wid >> 1, wc = wid & 1;
    const int lr = lane & 15;
    const int ko = (lane >> 4) * 8;
    const size_t rowBase = (size_t)blockIdx.x * 128;
    const size_t colBase = (size_t)blockIdx.y * 128;
    const int r0 = tid >> 2;
    const int c0 = (tid & 3) * 8;
    const float* a_src = A + (rowBase + r0) * lda + c0;
    const bf16_t* w_src = W + (colBase + r0) * ldw + c0;
    f32x4 acc[4][4];
#pragma unroll
    for (int m = 0; m < 4; ++m)
#pragma unroll
        for (int n = 0; n < 4; ++n) {
            acc[m][n][0] = 0.f; acc[m][n][1] = 0.f;
            acc[m][n][2] = 0.f; acc[m][n][3] = 0.f;
        }
    for (int k0 = 0; k0 < K; k0 += 32) {
        float4 a0 = *reinterpret_cast<const float4*>(a_src + k0);
        float4 a1 = *reinterpret_cast<const float4*>(a_src + k0 + 4);
        float4 a2 = *reinterpret_cast<const float4*>(a_src + (size_t)64 * lda + k0);
        float4 a3 = *reinterpret_cast<const float4*>(a_src + (size_t)64 * lda + k0 + 4);
        __syncthreads();
        gload_lds16(w_src + k0, Bs + tid * 8);
        gload_lds16(w_src + (size_t)64 * ldw + k0, Bs + 2048 + tid * 8);
        bf16x8 p0, p1;
        p0[0] = (__bf16)a0.x; p0[1] = (__bf16)a0.y; p0[2] = (__bf16)a0.z; p0[3] = (__bf16)a0.w;
        p0[4] = (__bf16)a1.x; p0[5] = (__bf16)a1.y; p0[6] = (__bf16)a1.z; p0[7] = (__bf16)a1.w;
        p1[0] = (__bf16)a2.x; p1[1] = (__bf16)a2.y; p1[2] = (__bf16)a2.z; p1[3] = (__bf16)a2.w;
        p1[4] = (__bf16)a3.x; p1[5] = (__bf16)a3.y; p1[6] = (__bf16)a3.z; p1[7] = (__bf16)a3.w;
        *reinterpret_cast<bf16x8*>(As + tid * 8) = p0;
        *reinterpret_cast<bf16x8*>(As + 2048 + tid * 8) = p1;
        __syncthreads();
        bf16x8 af[4], bfr[4];
#pragma unroll
        for (int m = 0; m < 4; ++m)
            af[m] = *reinterpret_cast<const bf16x8*>(As + (wr * 64 + m * 16 + lr) * 32 + ko);
#pragma unroll
        for (int n = 0; n < 4; ++n)
            bfr[n] = *reinterpret_cast<const bf16x8*>(Bs + (wc * 64 + n * 16 + lr) * 32 + ko);
#pragma unroll
        for (int m = 0; m < 4; ++m)
#pragma unroll
            for (int n = 0; n < 4; ++n)
                acc[m][n] = __builtin_amdgcn_mfma_f32_16x16x32_bf16(af[m], bfr[n], acc[m][n], 0, 0, 0);
    }
    const int rj = (lane >> 4) * 4;
#pragma unroll
    for (int n = 0; n < 4; ++n) {
        const int col = (int)colBase + wc * 64 + n * 16 + lr;
        const float bv = bias ? bias[col] : 0.f;
#pragma unroll
        for (int m = 0; m < 4; ++m) {
            const size_t r = rowBase + wr * 64 + m * 16 + rj;
#pragma unroll
            for (int j = 0; j < 4; ++j)
                Cb[(r + j) * ldc + col] = (__bf16)(acc[m][n][j] + bv);
        }
    }
}

// ---------------- 128x128 LDS-staged GEMM, bf16 A, f32 out (+bias) ----------------
__global__ __launch_bounds__(256) void gemm128_bias(
    const bf16_t* __restrict__ A, int lda,
    const bf16_t* __restrict__ W, int ldw,
    const float* __restrict__ bias,
    float* __restrict__ Cf, int ldc, int K) {
    __shared__ __align__(16) bf16_t As[128 * 32];
    __shared__ __align__(16) bf16_t Bs[128 * 32];
    const int tid = threadIdx.x;
    const int wid = tid >> 6, lane = tid & 63;
    const int wr = wid >> 1, wc = wid & 1;
    const int lr = lane & 15;
    const int ko = (lane >> 4) * 8;
    const size_t rowBase = (size_t)blockIdx.x * 128;
    const size_t colBase = (size_t)blockIdx.y * 128;
    const int r0 = tid >> 2;
    const int c0 = (tid & 3) * 8;
    const bf16_t* a_src = A + (rowBase + r0) * lda + c0;
    const bf16_t* w_src = W + (colBase + r0) * ldw + c0;
    f32x4 acc[4][4];
#pragma unroll
    for (int m = 0; m < 4; ++m)
#pragma unroll
        for (int n = 0; n < 4; ++n) {
            acc[m][n][0] = 0.f; acc[m][n][1] = 0.f;
            acc[m][n][2] = 0.f; acc[m][n][3] = 0.f;
        }
    for (int k0 = 0; k0 < K; k0 += 32) {
        __syncthreads();
        gload_lds16(a_src + k0, As + tid * 8);
        gload_lds16(a_src + (size_t)64 * lda + k0, As + 2048 + tid * 8);
        gload_lds16(w_src + k0, Bs + tid * 8);
        gload_lds16(w_src + (size_t)64 * ldw + k0, Bs + 2048 + tid * 8);
        __syncthreads();
        bf16x8 af[4], bfr[4];
#pragma unroll
        for (int m = 0; m < 4; ++m)
            af[m] = *reinterpret_cast<const bf16x8*>(As + (wr * 64 + m * 16 + lr) * 32 + ko);
#pragma unroll
        for (int n = 0; n < 4; ++n)
            bfr[n] = *reinterpret_cast<const bf16x8*>(Bs + (wc * 64 + n * 16 + lr) * 32 + ko);
#pragma unroll
        for (int m = 0; m < 4; ++m)
#pragma unroll
            for (int n = 0; n < 4; ++n)
                acc[m][n] = __builtin_amdgcn_mfma_f32_16x16x32_bf16(af[m], bfr[n], acc[m][n], 0, 0, 0);
    }
    const int rj = (lane >> 4) * 4;
#pragma unroll
    for (int n = 0; n < 4; ++n) {
        const int col = (int)colBase + wc * 64 + n * 16 + lr;
        const float bv = bias ? bias[col] : 0.f;
#pragma unroll
        for (int m = 0; m < 4; ++m) {
            const size_t r = rowBase + wr * 64 + m * 16 + rj;
#pragma unroll
            for (int j = 0; j < 4; ++j)
                Cf[(r + j) * ldc + col] = acc[m][n][j] + bv;
        }
    }
}

// ---------------- small direct GEMM (WcT fold only) ----------------
__global__ __launch_bounds__(256) void gemm_bt(
    const bf16_t* __restrict__ A, int lda, int aZ,
    const bf16_t* __restrict__ W, int ldw, int wZ,
    bf16_t* __restrict__ Cb, int ldc, int cZ,
    int M, int N, int K) {
    const int wid = threadIdx.x >> 6;
    const int lane = threadIdx.x & 63;
    const int lr = lane & 15;
    const int kk = (lane >> 4) * 8;
    const int row0 = blockIdx.x * 64 + wid * 16;
    const int col0 = blockIdx.y * 64;
    A += (size_t)blockIdx.z * aZ;
    W += (size_t)blockIdx.z * wZ;
    const bf16_t* a_ptr = A + (size_t)(row0 + lr) * lda + kk;
    const bf16_t* w_ptr = W + (size_t)(col0 + lr) * ldw + kk;
    f32x4 acc[4];
#pragma unroll
    for (int t = 0; t < 4; ++t) { acc[t][0] = 0.f; acc[t][1] = 0.f; acc[t][2] = 0.f; acc[t][3] = 0.f; }
    bool colv[4];
#pragma unroll
    for (int t = 0; t < 4; ++t) colv[t] = (col0 + t * 16 + lr) < N;
    for (int k0 = 0; k0 < K; k0 += 32) {
        bf16x8 a = *reinterpret_cast<const bf16x8*>(a_ptr + k0);
#pragma unroll
        for (int t = 0; t < 4; ++t) {
            bf16x8 b;
            if (colv[t]) b = *reinterpret_cast<const bf16x8*>(w_ptr + (size_t)t * 16 * ldw + k0);
            else b = zero8();
            acc[t] = __builtin_amdgcn_mfma_f32_16x16x32_bf16(a, b, acc[t], 0, 0, 0);
        }
    }
    const int rb = (lane >> 4) * 4;
    Cb += (size_t)blockIdx.z * cZ;
#pragma unroll
    for (int t = 0; t < 4; ++t) {
        int col = col0 + t * 16 + lr;
        if (col >= N) continue;
#pragma unroll
        for (int j = 0; j < 4; ++j) {
            int r = row0 + rb + j;
            Cb[(size_t)r * ldc + col] = (__bf16)acc[t][j];
        }
    }
}

// ---------------- predict addressing: sim -> softmax -> addr bf16 [N,896] ----------------
__global__ __launch_bounds__(256) void addr_predict(const bf16_t* __restrict__ qp,
                                                    const bf16_t* __restrict__ keyn,
                                                    bf16_t* __restrict__ addr) {
    const int wid = threadIdx.x >> 6, lane = threadIdx.x & 63;
    const int lr = lane & 15, kk = (lane >> 4) * 8;
    const int h = blockIdx.y;
    const int row0 = blockIdx.x * 64 + wid * 16;
    const bf16_t* a_ptr = qp + (size_t)(row0 + lr) * 512 + h * 64 + kk;
    bf16x8 a0 = *reinterpret_cast<const bf16x8*>(a_ptr);
    bf16x8 a1 = *reinterpret_cast<const bf16x8*>(a_ptr + 32);
    float ssq = 0.f;
#pragma unroll
    for (int j = 0; j < 8; ++j) {
        float x = (float)a0[j], y = (float)a1[j];
        ssq += x * x + y * y;
    }
    ssq += __shfl_xor(ssq, 16);
    ssq += __shfl_xor(ssq, 32);
    const float invq = 1.f / fmaxf(sqrtf(ssq), 1e-12f);
    f32x4 acc[7];
#pragma unroll
    for (int t = 0; t < 7; ++t) {
        const bf16_t* b_ptr = keyn + (size_t)(h * 112 + t * 16 + lr) * 64 + kk;
        bf16x8 b0 = *reinterpret_cast<const bf16x8*>(b_ptr);
        bf16x8 b1 = *reinterpret_cast<const bf16x8*>(b_ptr + 32);
        f32x4 c; c[0] = 0.f; c[1] = 0.f; c[2] = 0.f; c[3] = 0.f;
        c = __builtin_amdgcn_mfma_f32_16x16x32_bf16(a0, b0, c, 0, 0, 0);
        c = __builtin_amdgcn_mfma_f32_16x16x32_bf16(a1, b1, c, 0, 0, 0);
        acc[t] = c;
    }
    const int rb = (lane >> 4) * 4;
    float iq[4];
#pragma unroll
    for (int j = 0; j < 4; ++j) iq[j] = __shfl(invq, rb + j);
#pragma unroll
    for (int j = 0; j < 4; ++j) {
        float m = -1e30f;
#pragma unroll
        for (int t = 0; t < 7; ++t) { acc[t][j] *= iq[j] * RADIUS_F; m = fmaxf(m, acc[t][j]); }
#pragma unroll
        for (int o = 1; o < 16; o <<= 1) m = fmaxf(m, __shfl_xor(m, o));
        float s = 0.f;
#pragma unroll
        for (int t = 0; t < 7; ++t) { float e = __expf(acc[t][j] - m); acc[t][j] = e; s += e; }
#pragma unroll
        for (int o = 1; o < 16; o <<= 1) s += __shfl_xor(s, o);
        const float rs = 1.f / s;
#pragma unroll
        for (int t = 0; t < 7; ++t) acc[t][j] *= rs;
    }
#pragma unroll
    for (int t = 0; t < 7; ++t)
#pragma unroll
        for (int j = 0; j < 4; ++j)
            addr[(size_t)(row0 + rb + j) * 896 + h * 112 + t * 16 + lr] = (__bf16)acc[t][j];
}

// ---------------- fused recon sim GEMM + softmax -> addr2 [M][128] ----------------
__global__ __launch_bounds__(256, 2) void gemm_sim_softmax(
    const bf16_t* __restrict__ vp,   // [M][512]
    const bf16_t* __restrict__ mvb,  // [128][512] (rows 112..127 zero)
    const float* __restrict__ invmv, // [112]
    bf16_t* __restrict__ addr2) {    // [M][128]
    __shared__ __align__(16) bf16_t As[2][128 * 32];
    __shared__ __align__(16) bf16_t Bs[2][128 * 32];
    const int tid = threadIdx.x;
    const int wid = tid >> 6, lane = tid & 63;
    const int lr = lane & 15, hi = lane >> 4;
    const int ko = hi * 8;
    const size_t rowBase = (size_t)blockIdx.x * 128;
    const int r0 = tid >> 2, c0 = (tid & 3) * 8;
    const bf16_t* a_src = vp + (rowBase + r0) * 512 + c0;
    const bf16_t* b_src = mvb + (size_t)r0 * 512 + c0;
    f32x4 acc[2][8];
#pragma unroll
    for (int m = 0; m < 2; ++m)
#pragma unroll
        for (int n = 0; n < 8; ++n) {
            acc[m][n][0] = 0.f; acc[m][n][1] = 0.f;
            acc[m][n][2] = 0.f; acc[m][n][3] = 0.f;
        }
    float ssq[2] = {0.f, 0.f};
    auto stage = [&](int buf, int ks) {
        const int k0 = ks * 32;
        gload_lds16(a_src + k0, &As[buf][tid * 8]);
        gload_lds16(a_src + (size_t)64 * 512 + k0, &As[buf][2048 + tid * 8]);
        gload_lds16(b_src + k0, &Bs[buf][tid * 8]);
        gload_lds16(b_src + (size_t)64 * 512 + k0, &Bs[buf][2048 + tid * 8]);
    };
    stage(0, 0);
    drain_barrier();
    int cur = 0;
    for (int ks = 0; ks < 16; ++ks) {
        if (ks < 15) stage(cur ^ 1, ks + 1);
        bf16x8 af[2], bfr[8];
#pragma unroll
        for (int m = 0; m < 2; ++m)
            af[m] = *reinterpret_cast<const bf16x8*>(&As[cur][(wid * 32 + m * 16 + lr) * 32 + ko]);
#pragma unroll
        for (int n = 0; n < 8; ++n)
            bfr[n] = *reinterpret_cast<const bf16x8*>(&Bs[cur][(n * 16 + lr) * 32 + ko]);
#pragma unroll
        for (int m = 0; m < 2; ++m) {
#pragma unroll
            for (int j = 0; j < 8; ++j) { float x = (float)af[m][j]; ssq[m] += x * x; }
#pragma unroll
            for (int n = 0; n < 8; ++n)
                acc[m][n] = __builtin_amdgcn_mfma_f32_16x16x32_bf16(af[m], bfr[n], acc[m][n], 0, 0, 0);
        }
        drain_barrier();
        cur ^= 1;
    }
#pragma unroll
    for (int m = 0; m < 2; ++m) {
        ssq[m] += __shfl_xor(ssq[m], 16);
        ssq[m] += __shfl_xor(ssq[m], 32);
        ssq[m] = 1.f / fmaxf(sqrtf(ssq[m]), 1e-12f);
    }
    const int rb = hi * 4;
    float imv[7];
#pragma unroll
    for (int n = 0; n < 7; ++n) imv[n] = invmv[n * 16 + lr];
#pragma unroll
    for (int m = 0; m < 2; ++m)
#pragma unroll
        for (int j = 0; j < 4; ++j) {
            const float iq = __shfl(ssq[m], (lane & 48) | (rb + j));
            float x[7];
            float mx = -1e30f;
#pragma unroll
            for (int n = 0; n < 7; ++n) {
                x[n] = acc[m][n][j] * iq * imv[n] * RADIUS_F;
                mx = fmaxf(mx, x[n]);
            }
#pragma unroll
            for (int o = 1; o < 16; o <<= 1) mx = fmaxf(mx, __shfl_xor(mx, o));
            float s = 0.f;
#pragma unroll
            for (int n = 0; n < 7; ++n) { x[n] = __expf(x[n] - mx); s += x[n]; }
#pragma unroll
            for (int o = 1; o < 16; o <<= 1) s += __shfl_xor(s, o);
            const float rs = 1.f / s;
            const size_t row = rowBase + wid * 32 + m * 16 + rb + j;
#pragma unroll
            for (int n = 0; n < 7; ++n)
                addr2[row * 128 + n * 16 + lr] = (__bf16)(x[n] * rs);
            addr2[row * 128 + 112 + lr] = (__bf16)0.f;
        }
}

// ---------------- streaming LN (predict): 4 rows/wave, 16 rows/block ----------------
// io = LN1(query + io) in place; grid = 32768/16 = 2048
__global__ __launch_bounds__(256) void ln_stream(
    float* __restrict__ io, const float* __restrict__ query,
    const float* __restrict__ g, const float* __restrict__ b) {
    const int wid = threadIdx.x >> 6, lane = threadIdx.x & 63;
    const size_t row0 = (size_t)blockIdx.x * 16 + wid * 4;
    const int c1 = lane * 4, c2 = 256 + lane * 4;
    float4 x1[4], x2[4];
    float s1[4], s2[4];
#pragma unroll
    for (int r = 0; r < 4; ++r) {
        const size_t base = (row0 + r) * 512;
        float4 a1 = *reinterpret_cast<const float4*>(io + base + c1);
        float4 a2 = *reinterpret_cast<const float4*>(io + base + c2);
        float4 q1 = *reinterpret_cast<const float4*>(query + base + c1);
        float4 q2 = *reinterpret_cast<const float4*>(query + base + c2);
        x1[r] = make_float4(a1.x + q1.x, a1.y + q1.y, a1.z + q1.z, a1.w + q1.w);
        x2[r] = make_float4(a2.x + q2.x, a2.y + q2.y, a2.z + q2.z, a2.w + q2.w);
        s1[r] = x1[r].x + x1[r].y + x1[r].z + x1[r].w + x2[r].x + x2[r].y + x2[r].z + x2[r].w;
        s2[r] = x1[r].x * x1[r].x + x1[r].y * x1[r].y + x1[r].z * x1[r].z + x1[r].w * x1[r].w +
                x2[r].x * x2[r].x + x2[r].y * x2[r].y + x2[r].z * x2[r].z + x2[r].w * x2[r].w;
    }
    // 8 independent reduction chains, interleaved (single 6-deep swizzle latency)
#pragma unroll
    for (int o = 1; o < 64; o <<= 1)
#pragma unroll
        for (int r = 0; r < 4; ++r) {
            s1[r] += __shfl_xor(s1[r], o);
            s2[r] += __shfl_xor(s2[r], o);
        }
    const float4 g1v = *reinterpret_cast<const float4*>(g + c1);
    const float4 g2v = *reinterpret_cast<const float4*>(g + c2);
    const float4 b1v = *reinterpret_cast<const float4*>(b + c1);
    const float4 b2v = *reinterpret_cast<const float4*>(b + c2);
#pragma unroll
    for (int r = 0; r < 4; ++r) {
        const size_t base = (row0 + r) * 512;
        const float mu = s1[r] * (1.f / 512.f);
        const float rs = rsqrtf(s2[r] * (1.f / 512.f) - mu * mu + LN_EPS);
        float4 o1 = make_float4((x1[r].x - mu) * rs * g1v.x + b1v.x,
                                (x1[r].y - mu) * rs * g1v.y + b1v.y,
                                (x1[r].z - mu) * rs * g1v.z + b1v.z,
                                (x1[r].w - mu) * rs * g1v.w + b1v.w);
        float4 o2 = make_float4((x2[r].x - mu) * rs * g2v.x + b2v.x,
                                (x2[r].y - mu) * rs * g2v.y + b2v.y,
                                (x2[r].z - mu) * rs * g2v.z + b2v.z,
                                (x2[r].w - mu) * rs * g2v.w + b2v.w);
        *reinterpret_cast<float4*>(io + base + c1) = o1;
        *reinterpret_cast<float4*>(io + base + c2) = o2;
    }
}

// ---------------- streaming recon epilogue: 4 rows/wave, no global atomics ----------------
// io = LN1(query + LN3(io)); rrpart[blockIdx.x] = sum over block rows of |1-cos(io,value)|
__global__ __launch_bounds__(256) void recon_ep_stream(
    float* __restrict__ io,
    const float* __restrict__ query, const float* __restrict__ value,
    const float* __restrict__ g3, const float* __restrict__ b3,
    const float* __restrict__ g1, const float* __restrict__ b1,
    float* __restrict__ rrpart) {
    const int wid = threadIdx.x >> 6, lane = threadIdx.x & 63;
    const size_t row0 = (size_t)blockIdx.x * 16 + wid * 4;
    const int c1 = lane * 4, c2 = 256 + lane * 4;
    float4 a1[4], a2[4];
    float sa[4], sa2[4], sav[4], sv2[4];
#pragma unroll
    for (int r = 0; r < 4; ++r) {
        const size_t base = (row0 + r) * 512;
        a1[r] = *reinterpret_cast<const float4*>(io + base + c1);
        a2[r] = *reinterpret_cast<const float4*>(io + base + c2);
        float4 v1 = *reinterpret_cast<const float4*>(value + base + c1);
        float4 v2 = *reinterpret_cast<const float4*>(value + base + c2);
        sa[r] = a1[r].x + a1[r].y + a1[r].z + a1[r].w + a2[r].x + a2[r].y + a2[r].z + a2[r].w;
        sa2[r] = a1[r].x * a1[r].x + a1[r].y * a1[r].y + a1[r].z * a1[r].z + a1[r].w * a1[r].w +
                 a2[r].x * a2[r].x + a2[r].y * a2[r].y + a2[r].z * a2[r].z + a2[r].w * a2[r].w;
        sav[r] = a1[r].x * v1.x + a1[r].y * v1.y + a1[r].z * v1.z + a1[r].w * v1.w +
                 a2[r].x * v2.x + a2[r].y * v2.y + a2[r].z * v2.z + a2[r].w * v2.w;
        sv2[r] = v1.x * v1.x + v1.y * v1.y + v1.z * v1.z + v1.w * v1.w +
                 v2.x * v2.x + v2.y * v2.y + v2.z * v2.z + v2.w * v2.w;
    }
#pragma unroll
    for (int o = 1; o < 64; o <<= 1)
#pragma unroll
        for (int r = 0; r < 4; ++r) {
            sa[r] += __shfl_xor(sa[r], o);
            sa2[r] += __shfl_xor(sa2[r], o);
            sav[r] += __shfl_xor(sav[r], o);
            sv2[r] += __shfl_xor(sv2[r], o);
        }
    float rrw = 0.f;
#pragma unroll
    for (int r = 0; r < 4; ++r) {
        const float na = fmaxf(sqrtf(sa2[r]), 1e-12f);
        const float nv = fmaxf(sqrtf(sv2[r]), 1e-12f);
        rrw += fabsf(1.f - sav[r] / (na * nv));
    }
    // phase 2: x = query + LN3(a)
    const float4 g3a = *reinterpret_cast<const float4*>(g3 + c1);
    const float4 g3b = *reinterpret_cast<const float4*>(g3 + c2);
    const float4 b3a = *reinterpret_cast<const float4*>(b3 + c1);
    const float4 b3b = *reinterpret_cast<const float4*>(b3 + c2);
    float s1[4], s2[4];
#pragma unroll
    for (int r = 0; r < 4; ++r) {
        const size_t base = (row0 + r) * 512;
        const float mu3 = sa[r] * (1.f / 512.f);
        const float r3 = rsqrtf(sa2[r] * (1.f / 512.f) - mu3 * mu3 + LN_EPS);
        float4 q1 = *reinterpret_cast<const float4*>(query + base + c1);
        float4 q2 = *reinterpret_cast<const float4*>(query + base + c2);
        a1[r] = make_float4(q1.x + (a1[r].x - mu3) * r3 * g3a.x + b3a.x,
                            q1.y + (a1[r].y - mu3) * r3 * g3a.y + b3a.y,
                            q1.z + (a1[r].z - mu3) * r3 * g3a.z + b3a.z,
                            q1.w + (a1[r].w - mu3) * r3 * g3a.w + b3a.w);
        a2[r] = make_float4(q2.x + (a2[r].x - mu3) * r3 * g3b.x + b3b.x,
                            q2.y + (a2[r].y - mu3) * r3 * g3b.y + b3b.y,
                            q2.z + (a2[r].z - mu3) * r3 * g3b.z + b3b.z,
                            q2.w + (a2[r].w - mu3) * r3 * g3b.w + b3b.w);
        s1[r] = a1[r].x + a1[r].y + a1[r].z + a1[r].w + a2[r].x + a2[r].y + a2[r].z + a2[r].w;
        s2[r] = a1[r].x * a1[r].x + a1[r].y * a1[r].y + a1[r].z * a1[r].z + a1[r].w * a1[r].w +
                a2[r].x * a2[r].x + a2[r].y * a2[r].y + a2[r].z * a2[r].z + a2[r].w * a2[r].w;
    }
#pragma unroll
    for (int o = 1; o < 64; o <<= 1)
#pragma unroll
        for (int r = 0; r < 4; ++r) {
            s1[r] += __shfl_xor(s1[r], o);
            s2[r] += __shfl_xor(s2[r], o);
        }
    const float4 g1a = *reinterpret_cast<const float4*>(g1 + c1);
    const float4 g1b = *reinterpret_cast<const float4*>(g1 + c2);
    const float4 b1a = *reinterpret_cast<const float4*>(b1 + c1);
    const float4 b1b = *reinterpret_cast<const float4*>(b1 + c2);
#pragma unroll
    for (int r = 0; r < 4; ++r) {
        const size_t base = (row0 + r) * 512;
        const float mu = s1[r] * (1.f / 512.f);
        const float rs = rsqrtf(s2[r] * (1.f / 512.f) - mu * mu + LN_EPS);
        float4 o1 = make_float4((a1[r].x - mu) * rs * g1a.x + b1a.x,
                                (a1[r].y - mu) * rs * g1a.y + b1a.y,
                                (a1[r].z - mu) * rs * g1a.z + b1a.z,
                                (a1[r].w - mu) * rs * g1a.w + b1a.w);
        float4 o2 = make_float4((a2[r].x - mu) * rs * g1b.x + b1b.x,
                                (a2[r].y - mu) * rs * g1b.y + b1b.y,
                                (a2[r].z - mu) * rs * g1b.z + b1b.z,
                                (a2[r].w - mu) * rs * g1b.w + b1b.w);
        *reinterpret_cast<float4*>(io + base + c1) = o1;
        *reinterpret_cast<float4*>(io + base + c2) = o2;
    }
    // per-block loss partial (no global atomic)
    __shared__ float rred[4];
    if (lane == 0) rred[wid] = rrw;
    __syncthreads();
    if (threadIdx.x == 0)
        rrpart[blockIdx.x] = rred[0] + rred[1] + rred[2] + rred[3];
}

// sum 2048 block partials -> loss_slots[0]
__global__ __launch_bounds__(256) void reduce_part_k(const float* __restrict__ part,
                                                     float* __restrict__ out) {
    float s = 0.f;
    for (int i = threadIdx.x; i < 2048; i += 256) s += part[i];
    s = wave_sum(s);
    __shared__ float red[4];
    const int wid = threadIdx.x >> 6, lane = threadIdx.x & 63;
    if (lane == 0) red[wid] = s;
    __syncthreads();
    if (threadIdx.x == 0)
        out[0] = (red[0] + red[1] + red[2] + red[3]) * (1.f / 32768.f);
}

extern "C" void kernel_launch(void* const* d_in, const int* in_sizes, int n_in,
                              void* d_out, int out_size, void* d_ws, size_t ws_size,
                              hipStream_t stream) {
    const float* query = (const float*)d_in[0];
    const float* value = (const float*)d_in[1];
    const float* mem_key = (const float*)d_in[2];
    const float* mem_value = (const float*)d_in[3];
    const float* q_w = (const float*)d_in[4];
    const float* q_b = (const float*)d_in[5];
    const float* v_w = (const float*)d_in[6];
    const float* v_b = (const float*)d_in[7];
    const float* out_w = (const float*)d_in[8];
    const float* out_b = (const float*)d_in[9];
    const float* ln1_g = (const float*)d_in[10];
    const float* ln1_b = (const float*)d_in[11];
    const float* ln3_g = (const float*)d_in[12];
    const float* ln3_b = (const float*)d_in[13];
    float* out = (float*)d_out;

    char* ws = (char*)d_ws;
    size_t off = 0;
    auto alloc = [&](size_t bytes) {
        void* p = ws + off;
        off += (bytes + 255) & ~(size_t)255;
        return p;
    };
    bf16_t* bufB = (bf16_t*)alloc(16777216ull * 2);    // qp_bf16, then v_proj_bf16
    bf16_t* addr = (bf16_t*)alloc(32768ull * 896 * 2); // addr, later addr2
    bf16_t* qwb = (bf16_t*)alloc(262144ull * 2);
    bf16_t* vwb = (bf16_t*)alloc(262144ull * 2);
    bf16_t* owb = (bf16_t*)alloc(2097152ull * 2);
    bf16_t* wct = (bf16_t*)alloc(896ull * 512 * 2);    // WcT[512][896]
    bf16_t* keyn = (bf16_t*)alloc(896ull * 64 * 2);
    bf16_t* mvb = (bf16_t*)alloc(128ull * 512 * 2);    // padded to 128 rows
    bf16_t* mvT = (bf16_t*)alloc(512ull * 128 * 2);
    float* invmv = (float*)alloc(112 * 4);
    float* rrpart = (float*)alloc(2048 * 4);
    bf16_t* addr2 = addr;

    float* f_predict = out;               // also attn_out staging (f32)
    float* f_recon = out + 16777216;      // also attn_recon staging (f32)
    float* loss_slots = out + 33554432;   // [recon_loss, contrastive_loss]

    // prep
    cast_k<<<256, 256, 0, stream>>>(q_w, qwb, 65536);
    cast_k<<<256, 256, 0, stream>>>(v_w, vwb, 65536);
    cast_k<<<2048, 256, 0, stream>>>(out_w, owb, 524288);
    keyn_k<<<224, 256, 0, stream>>>(mem_key, keyn);
    mv_prep_k<<<128, 256, 0, stream>>>(mem_value, mvb, invmv, loss_slots);
    mvT_k<<<256, 256, 0, stream>>>(mem_value, mvT);
    contrastive_k<<<112, 256, 0, stream>>>(mem_value, invmv, loss_slots + 1);
    // WcT[d][h*112+s] = sum_j out_w[d][h*512+j] * mem_value[s][j]
    gemm_bt<<<dim3(8, 2, 8), 256, 0, stream>>>(owb, 4096, 512, mvb, 512, 0,
                                               wct, 896, 112, 512, 112, 512);
    // predict branch
    gemm128_f32a<<<dim3(256, 4), 256, 0, stream>>>(query, 512, qwb, 512, q_b,
                                                   bufB, 512, 512);
    addr_predict<<<dim3(512, 8), 256, 0, stream>>>(bufB, keyn, addr);
    gemm128_bias<<<dim3(256, 4), 256, 0, stream>>>(addr, 896, wct, 896, out_b,
                                                   f_predict, 512, 896);
    ln_stream<<<2048, 256, 0, stream>>>(f_predict, query, ln1_g, ln1_b);
    // recon branch
    gemm128_f32a<<<dim3(256, 4), 256, 0, stream>>>(value, 512, vwb, 512, v_b,
                                                   bufB, 512, 512);
    gemm_sim_softmax<<<256, 256, 0, stream>>>(bufB, mvb, invmv, addr2);
    gemm128_bias<<<dim3(256, 4), 256, 0, stream>>>(addr2, 128, mvT, 128,
                                                   (const float*)nullptr,
                                                   f_recon, 512, 128);
    recon_ep_stream<<<2048, 256, 0, stream>>>(f_recon, query, value,
                                              ln3_g, ln3_b, ln1_g, ln1_b,
                                              rrpart);
    reduce_part_k<<<1, 256, 0, stream>>>(rrpart, loss_slots);
}